// Round 11
// baseline (244.837 us; speedup 1.0000x reference)
//
#include <hip/hip_runtime.h>
#include <hip/hip_bf16.h>
#include <math.h>

// Problem constants (fixed by the reference file)
#define T_TOK 2048
#define H_DIM 1024
#define I_DIM 2048
#define E_NUM 8
#define TOPK  2
#define P_MAX (T_TOK * TOPK)   // 4096 (token, k) pairs
#define MAX_SLOTS 40           // max 128-row slots: 4096/128 + 8

typedef __bf16 bf16_t;
typedef __attribute__((ext_vector_type(8))) __bf16 bf16x8;
typedef __attribute__((ext_vector_type(4))) float  f32x4;

// global_load_lds: per-lane GLOBAL address, wave-uniform LDS base; lane n
// writes lds_base + n*16 bytes (m104/m108).
#define GLOAD_LDS16(gptr, lptr)                                                   \
    __builtin_amdgcn_global_load_lds(                                             \
        (const __attribute__((address_space(1))) void*)(gptr),                    \
        (__attribute__((address_space(3))) void*)(lptr), 16, 0, 0)

__device__ inline f32x4 zero4() {
    f32x4 z; z[0] = 0.f; z[1] = 0.f; z[2] = 0.f; z[3] = 0.f; return z;
}

__device__ inline bf16x8 cvt8(f32x4 a, f32x4 b) {
    bf16x8 o;
    o[0] = (bf16_t)a[0]; o[1] = (bf16_t)a[1]; o[2] = (bf16_t)a[2]; o[3] = (bf16_t)a[3];
    o[4] = (bf16_t)b[0]; o[5] = (bf16_t)b[1]; o[6] = (bf16_t)b[2]; o[7] = (bf16_t)b[3];
    return o;
}

// ---------------------------------------------------------------- init
__global__ void init_kernel(int* counts, int* cursor) {
    int i = threadIdx.x;
    if (i < E_NUM) { counts[i] = 0; cursor[i] = 0; }
}

// ---------------------------------------------------------------- router
__global__ void router_kernel(const float* __restrict__ gating,
                              int* __restrict__ expert_id,
                              float* __restrict__ wt,
                              int* __restrict__ counts) {
    int t = blockIdx.x * blockDim.x + threadIdx.x;
    if (t >= T_TOK) return;
    float l[E_NUM];
    float m = -1e30f;
    #pragma unroll
    for (int e = 0; e < E_NUM; e++) { l[e] = gating[t * E_NUM + e]; m = fmaxf(m, l[e]); }
    float p[E_NUM];
    #pragma unroll
    for (int e = 0; e < E_NUM; e++) p[e] = __expf(l[e] - m);
    int i0 = 0; float p0 = p[0];
    #pragma unroll
    for (int e = 1; e < E_NUM; e++) if (p[e] > p0) { p0 = p[e]; i0 = e; }
    int i1 = -1; float p1 = -1.f;
    #pragma unroll
    for (int e = 0; e < E_NUM; e++) if (e != i0 && p[e] > p1) { p1 = p[e]; i1 = e; }
    float inv = 1.f / (p0 + p1);
    expert_id[t * 2 + 0] = i0; wt[t * 2 + 0] = p0 * inv;
    expert_id[t * 2 + 1] = i1; wt[t * 2 + 1] = p1 * inv;
    atomicAdd(&counts[i0], 1);
    atomicAdd(&counts[i1], 1);
}

// ---------------------------------------------------------------- scan + tile map
__global__ void scan_kernel(const int* __restrict__ counts,
                            int* __restrict__ offsets,
                            int* __restrict__ tile_e, int* __restrict__ tile_m0,
                            int* __restrict__ n_slots) {
    if (threadIdx.x != 0 || blockIdx.x != 0) return;
    int off = 0;
    for (int e = 0; e < E_NUM; e++) { offsets[e] = off; off += counts[e]; }
    offsets[E_NUM] = off;
    int s = 0;
    for (int e = 0; e < E_NUM; e++)
        for (int m0 = offsets[e]; m0 < offsets[e + 1]; m0 += 128) {
            tile_e[s] = e; tile_m0[s] = m0; s++;
        }
    *n_slots = s;
}

// ---------------------------------------------------------------- scatter
__global__ void scatter_kernel(const int* __restrict__ expert_id,
                               const float* __restrict__ wt,
                               const int* __restrict__ offsets,
                               int* __restrict__ cursor,
                               int* __restrict__ pair_token,
                               int* __restrict__ pair_dst,
                               float* __restrict__ pair_wt) {
    int t = blockIdx.x * blockDim.x + threadIdx.x;
    if (t >= T_TOK) return;
    #pragma unroll
    for (int k = 0; k < TOPK; k++) {
        int e = expert_id[t * 2 + k];
        int p = offsets[e] + atomicAdd(&cursor[e], 1);
        pair_token[p] = t;
        pair_dst[p]   = t * 2 + k;
        pair_wt[p]    = wt[t * 2 + k];
    }
}

// ---------------------------------------------------------------- f32 -> bf16 convert
__global__ void convert_kernel(const float* __restrict__ src,
                               bf16_t* __restrict__ dst) {
    size_t base = ((size_t)blockIdx.x * blockDim.x + threadIdx.x) * 16;
    f32x4 v0 = *(const f32x4*)(src + base);
    f32x4 v1 = *(const f32x4*)(src + base + 4);
    f32x4 v2 = *(const f32x4*)(src + base + 8);
    f32x4 v3 = *(const f32x4*)(src + base + 12);
    *(bf16x8*)(dst + base)     = cvt8(v0, v1);
    *(bf16x8*)(dst + base + 8) = cvt8(v2, v3);
}

// ================================================================ GEMM engine
// 8-phase counted-vmcnt schedule (T3+T4+T5), plain HIP per m201/m248:
// BM=128 x BN=256, BK=64, 512 thr / 8 waves (2M x 4N), wave out = 64 rows x
// 64 B-rows, acc[4][4]. Triple-buffered LDS (3 x 48KB = 144KB) -> prefetch
// depth 2, vmcnt(6) once per K-tile, NEVER drained in-loop.
// Per K-tile, 4 phases; phase p = quadrant (pi=p>>1, pj=p&1):
//   {8 ds_read (2 A-frags + 2 B-frags, both K-halves) | 2 gload_lds for
//    tile t+2} -> s_barrier -> lgkmcnt(0)+sched_barrier(0) [rule #18] ->
//    setprio(1) 8 MFMA setprio(0) -> s_barrier (phase 3: vmcnt(lead) first).
// LDS rows = 128B = 8 granules, XOR-swizzle slot = g ^ (row&7) both sides.

#define G1_PHASE(p)                                                               \
    {                                                                             \
        const int pi = (p) >> 1, pj = (p) & 1;                                    \
        bf16x8 af[2][2], bf[2][2];                                                \
        _Pragma("unroll") for (int i2 = 0; i2 < 2; i2++) {                        \
            int row = wm * 64 + pi * 32 + i2 * 16 + l15;                          \
            _Pragma("unroll") for (int kh = 0; kh < 2; kh++)                      \
                af[i2][kh] = *(const bf16x8*)(sAb + row * 64 + (((kh * 4 + lg) ^ (row & 7)) << 3)); \
        }                                                                         \
        _Pragma("unroll") for (int j2 = 0; j2 < 2; j2++) {                        \
            int row = wn * 64 + pj * 32 + j2 * 16 + l15;                          \
            _Pragma("unroll") for (int kh = 0; kh < 2; kh++)                      \
                bf[j2][kh] = *(const bf16x8*)(sBb + row * 64 + (((kh * 4 + lg) ^ (row & 7)) << 3)); \
        }                                                                         \
        if ((p) == 0 && pf) {                                                     \
            GLOAD_LDS16(gA[0] + kpre, sAn + (w * 16) * 64);                       \
            GLOAD_LDS16(gA[1] + kpre, sAn + (w * 16 + 8) * 64);                   \
        }                                                                         \
        if ((p) == 1 && pf) {                                                     \
            GLOAD_LDS16(gB[0] + kpre, sBn + (w * 32) * 64);                       \
            GLOAD_LDS16(gB[1] + kpre, sBn + (w * 32 + 8) * 64);                   \
        }                                                                         \
        if ((p) == 2 && pf) {                                                     \
            GLOAD_LDS16(gB[2] + kpre, sBn + (w * 32 + 16) * 64);                  \
            GLOAD_LDS16(gB[3] + kpre, sBn + (w * 32 + 24) * 64);                  \
        }                                                                         \
        __builtin_amdgcn_s_barrier();                                             \
        asm volatile("s_waitcnt lgkmcnt(0)" ::: "memory");                        \
        __builtin_amdgcn_sched_barrier(0);                                        \
        __builtin_amdgcn_s_setprio(1);                                            \
        _Pragma("unroll") for (int i2 = 0; i2 < 2; i2++)                          \
            _Pragma("unroll") for (int j2 = 0; j2 < 2; j2++) {                    \
                acc[pi * 2 + i2][pj * 2 + j2] = __builtin_amdgcn_mfma_f32_16x16x32_bf16( \
                    af[i2][0], bf[j2][0], acc[pi * 2 + i2][pj * 2 + j2], 0, 0, 0);\
                acc[pi * 2 + i2][pj * 2 + j2] = __builtin_amdgcn_mfma_f32_16x16x32_bf16( \
                    af[i2][1], bf[j2][1], acc[pi * 2 + i2][pj * 2 + j2], 0, 0, 0);\
            }                                                                     \
        __builtin_amdgcn_s_setprio(0);                                            \
        if ((p) == 3) {                                                           \
            if (pf)       { asm volatile("s_waitcnt vmcnt(6)" ::: "memory"); }    \
            else if (t < NT - 1) { asm volatile("s_waitcnt vmcnt(0)" ::: "memory"); } \
        }                                                                         \
        __builtin_amdgcn_sched_barrier(0);                                        \
        __builtin_amdgcn_s_barrier();                                             \
    }

// ---------------------------------------------------------------- GEMM1 + SwiGLU
// B-tile = 256 permuted w1-rows: row r -> grp=r>>6, sub=r&63;
// sub<32: gate col c0+grp*32+sub, else up col (I_DIM+...). Wave wn's frags
// j=0,1 gate / j=2,3 up, SAME act col -> lane-local SwiGLU.
__global__ __launch_bounds__(512)
void gemm1_kernel(const bf16_t* __restrict__ hbf,
                  const bf16_t* __restrict__ w1bf,
                  const int* __restrict__ pair_token,
                  const int* __restrict__ offsets,
                  const int* __restrict__ tile_e,
                  const int* __restrict__ tile_m0,
                  const int* __restrict__ n_slots,
                  bf16_t* __restrict__ act) {
    __shared__ __align__(16) bf16_t sA[3][128][64];  // 48 KB
    __shared__ __align__(16) bf16_t sB[3][256][64];  // 96 KB

    int P = blockIdx.x;                    // 640 = 8 x 80
    int L = (P & 7) * 80 + (P >> 3);       // bijective chunked XCD swizzle
    int slot = L >> 4;
    int c0   = (L & 15) << 7;              // act cols [c0, c0+128)
    if (slot >= *n_slots) return;
    int e    = tile_e[slot];
    int m0   = tile_m0[slot];
    int mend = offsets[e + 1];
    const bf16_t* w1e = w1bf + (size_t)e * (2 * I_DIM) * H_DIM;

    int tid = threadIdx.x;
    int lane = tid & 63, w = tid >> 6;     // 8 waves
    int wm = w >> 2, wn = w & 3;           // 2M x 4N
    int l15 = lane & 15, lg = lane >> 4;
    int sr8 = lane >> 3, sg8 = lane & 7;
    int gcol = (sg8 ^ sr8) * 8;            // inverse-swizzled SOURCE granule

    // staging addresses (K-tile offset added in loop)
    const bf16_t* gA[2];
    #pragma unroll
    for (int i = 0; i < 2; i++) {
        int pr = m0 + w * 16 + i * 8 + sr8;
        int tok = (pr < mend) ? pair_token[pr] : 0;  // dummy, masked later
        gA[i] = hbf + (size_t)tok * H_DIM + gcol;
    }
    const bf16_t* gB[4];
    #pragma unroll
    for (int i = 0; i < 4; i++) {
        int r = w * 32 + i * 8 + sr8;
        int grp = r >> 6, sub = r & 63;
        int w1r = (sub < 32) ? (c0 + grp * 32 + sub) : (I_DIM + c0 + grp * 32 + sub - 32);
        gB[i] = w1e + (size_t)w1r * H_DIM + gcol;
    }

    f32x4 acc[4][4];  // [i][0..1]=gate, [i][2..3]=up (same cols)
    #pragma unroll
    for (int i = 0; i < 4; i++)
        #pragma unroll
        for (int j = 0; j < 4; j++) acc[i][j] = zero4();

    // prologue: stage tiles 0,1 into bufs 0,1
    #pragma unroll
    for (int i = 0; i < 2; i++) GLOAD_LDS16(gA[i], &sA[0][w * 16 + i * 8][0]);
    #pragma unroll
    for (int i = 0; i < 4; i++) GLOAD_LDS16(gB[i], &sB[0][w * 32 + i * 8][0]);
    #pragma unroll
    for (int i = 0; i < 2; i++) GLOAD_LDS16(gA[i] + 64, &sA[1][w * 16 + i * 8][0]);
    #pragma unroll
    for (int i = 0; i < 4; i++) GLOAD_LDS16(gB[i] + 64, &sB[1][w * 32 + i * 8][0]);
    asm volatile("s_waitcnt vmcnt(6)" ::: "memory");   // tile 0 landed
    __builtin_amdgcn_s_barrier();

    const int NT = H_DIM / 64;   // 16
    int ct = 0, cn = 2;
    for (int t = 0; t < NT; t++) {
        bool pf = (t + 2) < NT;
        int kpre = (t + 2) * 64;
        const bf16_t* sAb = &sA[ct][0][0];
        const bf16_t* sBb = &sB[ct][0][0];
        bf16_t* sAn = &sA[cn][0][0];
        bf16_t* sBn = &sB[cn][0][0];
        G1_PHASE(0) G1_PHASE(1) G1_PHASE(2) G1_PHASE(3)
        ct = (ct == 2) ? 0 : ct + 1;
        cn = (cn == 2) ? 0 : cn + 1;
    }

    // epilogue: act = silu(gate) * up
    #pragma unroll
    for (int i = 0; i < 4; i++) {
        #pragma unroll
        for (int rr = 0; rr < 4; rr++) {
            int m = m0 + wm * 64 + i * 16 + lg * 4 + rr;
            if (m < mend) {
                #pragma unroll
                for (int j = 0; j < 2; j++) {
                    float gv = acc[i][j][rr];
                    float uv = acc[i][2 + j][rr];
                    float sv = gv / (1.f + __expf(-gv));
                    act[(size_t)m * I_DIM + c0 + wn * 32 + j * 16 + l15] = (bf16_t)(sv * uv);
                }
            }
        }
    }
}

// ---------------------------------------------------------------- GEMM2 (+ scale, k-split)
// Same 8-phase engine, direct B mapping (row r -> out col n0+r), kz split 2.
__global__ __launch_bounds__(512)
void gemm2_kernel(const bf16_t* __restrict__ act,
                  const bf16_t* __restrict__ w2bf,
                  const int* __restrict__ offsets,
                  const int* __restrict__ tile_e,
                  const int* __restrict__ tile_m0,
                  const int* __restrict__ n_slots,
                  const int* __restrict__ pair_dst,
                  const float* __restrict__ pair_wt,
                  float* __restrict__ ybuf) {
    __shared__ __align__(16) bf16_t sA[3][128][64];
    __shared__ __align__(16) bf16_t sB[3][256][64];

    int P = blockIdx.x;                    // 320 = 8 x 40
    int L = (P & 7) * 40 + (P >> 3);
    int slot = L >> 3;
    int n0   = ((L >> 1) & 3) << 8;        // out cols [n0, n0+256)
    int kz   = L & 1;
    if (slot >= *n_slots) return;
    int kb   = kz << 10;                   // k-slice base (1024)
    int e    = tile_e[slot];
    int m0   = tile_m0[slot];
    int mend = offsets[e + 1];
    const bf16_t* w2e = w2bf + (size_t)e * H_DIM * I_DIM;

    int tid = threadIdx.x;
    int lane = tid & 63, w = tid >> 6;
    int wm = w >> 2, wn = w & 3;
    int l15 = lane & 15, lg = lane >> 4;
    int sr8 = lane >> 3, sg8 = lane & 7;
    int gcol = (sg8 ^ sr8) * 8;

    const bf16_t* gA[2];
    #pragma unroll
    for (int i = 0; i < 2; i++)   // rows >= mend read arena neighbors (masked)
        gA[i] = act + (size_t)(m0 + w * 16 + i * 8 + sr8) * I_DIM + kb + gcol;
    const bf16_t* gB[4];
    #pragma unroll
    for (int i = 0; i < 4; i++)
        gB[i] = w2e + (size_t)(n0 + w * 32 + i * 8 + sr8) * I_DIM + kb + gcol;

    f32x4 acc[4][4];
    #pragma unroll
    for (int i = 0; i < 4; i++)
        #pragma unroll
        for (int j = 0; j < 4; j++) acc[i][j] = zero4();

    #pragma unroll
    for (int i = 0; i < 2; i++) GLOAD_LDS16(gA[i], &sA[0][w * 16 + i * 8][0]);
    #pragma unroll
    for (int i = 0; i < 4; i++) GLOAD_LDS16(gB[i], &sB[0][w * 32 + i * 8][0]);
    #pragma unroll
    for (int i = 0; i < 2; i++) GLOAD_LDS16(gA[i] + 64, &sA[1][w * 16 + i * 8][0]);
    #pragma unroll
    for (int i = 0; i < 4; i++) GLOAD_LDS16(gB[i] + 64, &sB[1][w * 32 + i * 8][0]);
    asm volatile("s_waitcnt vmcnt(6)" ::: "memory");
    __builtin_amdgcn_s_barrier();

    const int NT = 1024 / 64;    // 16
    int ct = 0, cn = 2;
    for (int t = 0; t < NT; t++) {
        bool pf = (t + 2) < NT;
        int kpre = (t + 2) * 64;
        const bf16_t* sAb = &sA[ct][0][0];
        const bf16_t* sBb = &sB[ct][0][0];
        bf16_t* sAn = &sA[cn][0][0];
        bf16_t* sBn = &sB[cn][0][0];
        G1_PHASE(0) G1_PHASE(1) G1_PHASE(2) G1_PHASE(3)
        ct = (ct == 2) ? 0 : ct + 1;
        cn = (cn == 2) ? 0 : cn + 1;
    }

    float* ybufz = ybuf + (size_t)kz * P_MAX * H_DIM;
    #pragma unroll
    for (int i = 0; i < 4; i++) {
        #pragma unroll
        for (int rr = 0; rr < 4; rr++) {
            int m = m0 + wm * 64 + i * 16 + lg * 4 + rr;
            if (m < mend) {
                int   dst = pair_dst[m];
                float wv  = pair_wt[m];
                #pragma unroll
                for (int j = 0; j < 4; j++)
                    ybufz[(size_t)dst * H_DIM + n0 + wn * 64 + j * 16 + l15] = acc[i][j][rr] * wv;
            }
        }
    }
}

// ---------------------------------------------------------------- combine
__global__ void combine_kernel(const float* __restrict__ ybuf,
                               float* __restrict__ out) {
    int idx = blockIdx.x * 256 + threadIdx.x;   // one float4 each
    int t = idx >> 8;                           // 256 float4 per token row
    int h = idx & 255;
    const size_t SL = (size_t)P_MAX * H_DIM;
    const f32x4* y00 = (const f32x4*)(ybuf + (size_t)(t * 2)     * H_DIM) + h;
    const f32x4* y01 = (const f32x4*)(ybuf + (size_t)(t * 2 + 1) * H_DIM) + h;
    const f32x4* y10 = (const f32x4*)(ybuf + SL + (size_t)(t * 2)     * H_DIM) + h;
    const f32x4* y11 = (const f32x4*)(ybuf + SL + (size_t)(t * 2 + 1) * H_DIM) + h;
    f32x4 s = (*y00 + *y10) + (*y01 + *y11);
    ((f32x4*)out)[idx] = s;
}

// ---------------------------------------------------------------- launch
extern "C" void kernel_launch(void* const* d_in, const int* in_sizes, int n_in,
                              void* d_out, int out_size, void* d_ws, size_t ws_size,
                              hipStream_t stream) {
    const float* hidden = (const float*)d_in[0];
    const float* w1     = (const float*)d_in[1];
    const float* w2     = (const float*)d_in[2];
    const float* gating = (const float*)d_in[3];
    float* out = (float*)d_out;

    const size_t N0 = (size_t)T_TOK * H_DIM;             // hidden elems
    const size_t N1 = (size_t)E_NUM * 2 * I_DIM * H_DIM; // w1 elems
    const size_t N2 = (size_t)E_NUM * H_DIM * I_DIM;     // w2 elems

    char* ws = (char*)d_ws;
    size_t off = 0;
    auto alloc = [&](size_t bytes) -> void* {
        void* p = ws + off;
        off += (bytes + 255) & ~(size_t)255;
        return p;
    };
    // order matters: act must not be last (gemm2 A-staging over-reads <=520KB)
    float*  ybuf  = (float*)alloc((size_t)2 * P_MAX * H_DIM * sizeof(float));     // 33.6 MB (2 slices)
    bf16_t* act   = (bf16_t*)alloc((size_t)P_MAX * I_DIM * sizeof(bf16_t));       // 16.8 MB
    bf16_t* hbf   = (bf16_t*)alloc(N0 * sizeof(bf16_t));                          //  4.2 MB
    bf16_t* w1bf  = (bf16_t*)alloc(N1 * sizeof(bf16_t));                          // 67.1 MB
    bf16_t* w2bf  = (bf16_t*)alloc(N2 * sizeof(bf16_t));                          // 33.6 MB
    int*    expert_id  = (int*)alloc(P_MAX * sizeof(int));
    float*  wt         = (float*)alloc(P_MAX * sizeof(float));
    int*    pair_token = (int*)alloc(P_MAX * sizeof(int));
    int*    pair_dst   = (int*)alloc(P_MAX * sizeof(int));
    float*  pair_wt    = (float*)alloc(P_MAX * sizeof(float));
    int*    counts     = (int*)alloc(E_NUM * sizeof(int));
    int*    offsets    = (int*)alloc((E_NUM + 1) * sizeof(int));
    int*    cursor     = (int*)alloc(E_NUM * sizeof(int));
    int*    n_slots    = (int*)alloc(sizeof(int));
    int*    tile_e     = (int*)alloc(MAX_SLOTS * sizeof(int));
    int*    tile_m0    = (int*)alloc(MAX_SLOTS * sizeof(int));

    init_kernel<<<1, 64, 0, stream>>>(counts, cursor);
    router_kernel<<<(T_TOK + 255) / 256, 256, 0, stream>>>(gating, expert_id, wt, counts);
    scan_kernel<<<1, 1, 0, stream>>>(counts, offsets, tile_e, tile_m0, n_slots);
    scatter_kernel<<<(T_TOK + 255) / 256, 256, 0, stream>>>(expert_id, wt, offsets, cursor,
                                                            pair_token, pair_dst, pair_wt);
    convert_kernel<<<(int)(N0 / (256 * 16)), 256, 0, stream>>>(hidden, hbf);
    convert_kernel<<<(int)(N1 / (256 * 16)), 256, 0, stream>>>(w1, w1bf);
    convert_kernel<<<(int)(N2 / (256 * 16)), 256, 0, stream>>>(w2, w2bf);
    gemm1_kernel<<<MAX_SLOTS * 16, 512, 0, stream>>>(   // 640 = 8 x 80
        hbf, w1bf, pair_token, offsets, tile_e, tile_m0, n_slots, act);
    gemm2_kernel<<<MAX_SLOTS * 8, 512, 0, stream>>>(    // 320 = 8 x 40
        act, w2bf, offsets, tile_e, tile_m0, n_slots, pair_dst, pair_wt, ybuf);
    combine_kernel<<<(T_TOK * H_DIM / 4) / 256, 256, 0, stream>>>(ybuf, out);

    (void)in_sizes; (void)n_in; (void)out_size; (void)ws_size;
}